// Round 1
// baseline (1377.147 us; speedup 1.0000x reference)
//
#include <hip/hip_runtime.h>
#include <math.h>

#define CCH 256
#define NB 2
#define HEADS 64

// ---------------- workspace layout (float element offsets) ----------------
// pooled: 4*2*256
// q:      2*256*(4096+1024+256+64)   = 2785280
// k,v:    2*256*(4128+1056+288+96)   = 2850816 each
// attn:   2785280
// dsacc:  8
static const size_t OFF_POOLED = 0;
static const size_t OFF_Q      = 2048;
static const size_t OFF_K      = 2048 + 2785280;              // 2787328
static const size_t OFF_V      = 2787328 + 2850816;           // 5638144
static const size_t OFF_ATTN   = 5638144 + 2850816;           // 8488960
static const size_t OFF_DSACC  = 8488960 + 2785280;           // 11274240

static const size_t QOFF[4]  = {0, 2097152, 2621440, 2752512};   // 512*prefix(L)
static const size_t KVOFF[4] = {0, 2113536, 2654208, 2801664};   // 512*prefix(M)
static const int    LVL_L[4] = {4096, 1024, 256, 64};
static const size_t DS_OUT_OFF = 2785280;

// ---------------- pooled = mean over H*W of ds ----------------
// grid (256, 2, 4), block 64: one wave per (lvl, n, c)
__global__ void pooled_kernel(const float* __restrict__ d0, const float* __restrict__ d1,
                              const float* __restrict__ d2, const float* __restrict__ d3,
                              float* __restrict__ pooled) {
    int c = blockIdx.x, n = blockIdx.y, lvl = blockIdx.z;
    int t = threadIdx.x;  // 0..63
    const float* d = (lvl == 0) ? d0 : (lvl == 1) ? d1 : (lvl == 2) ? d2 : d3;
    int L = 4096 >> (2 * lvl);
    const float* p = d + ((size_t)n * CCH + c) * L;
    float s = 0.f;
    for (int i = t; i < L; i += 64) s += p[i];
    #pragma unroll
    for (int off = 32; off > 0; off >>= 1) s += __shfl_down(s, off);
    if (t == 0) pooled[(lvl * NB + n) * CCH + c] = s / (float)L;
}

// ---------------- ds token GEMV: key_tok / val_tok into k/v tails ----------
// grid (32, 2, 4), block 256. thread -> one j in [0,8192)
__global__ __launch_bounds__(256)
void dstok_kernel(const float* __restrict__ Wdsk, const float* __restrict__ bdsk,
                  const float* __restrict__ Wdsv, const float* __restrict__ bdsv,
                  const float* __restrict__ ds_gate, const float* __restrict__ pooled,
                  float* __restrict__ kbuf, float* __restrict__ vbuf) {
    int lvl = blockIdx.z, n = blockIdx.y;
    int j = blockIdx.x * 256 + threadIdx.x;
    const float4* wk = (const float4*)(Wdsk + ((size_t)lvl * 8192 + j) * CCH);
    const float4* wv = (const float4*)(Wdsv + ((size_t)lvl * 8192 + j) * CCH);
    const float4* pp = (const float4*)(pooled + (size_t)(lvl * NB + n) * CCH);
    float ak = 0.f, av = 0.f;
    #pragma unroll 8
    for (int c4 = 0; c4 < CCH / 4; c4++) {
        float4 p = pp[c4], a = wk[c4], b = wv[c4];
        ak += a.x * p.x + a.y * p.y + a.z * p.z + a.w * p.w;
        av += b.x * p.x + b.y * p.y + b.z * p.z + b.w * p.w;
    }
    ak += bdsk[lvl * 8192 + j];
    av += bdsv[lvl * 8192 + j];
    float gate = 1.f / (1.f + __expf(-ds_gate[lvl]));
    av *= gate;
    int o = j >> 5, tk = j & 31;
    int L = 4096 >> (2 * lvl);
    int M = L + 32;
    size_t kvoff = KVOFF[0];
    if (lvl == 1) kvoff = 2113536; else if (lvl == 2) kvoff = 2654208; else if (lvl == 3) kvoff = 2801664;
    size_t idx = kvoff + ((size_t)(n * CCH + o)) * M + L + tk;
    kbuf[idx] = ak;
    vbuf[idx] = av;
}

// ---------------- conv1x1 GEMM: Y[n,o,l] = sum_c W[o,c] X[n,c,l] + b[o] (+res)
// grid (L/64, 4, 2), block 256. tile 64o x 64l, 4x4 per thread, K-step 16.
__global__ __launch_bounds__(256)
void conv_kernel(const float* __restrict__ X, const float* __restrict__ W,
                 const float* __restrict__ b, float* __restrict__ Y,
                 const float* __restrict__ res, int L, int ldY) {
    __shared__ float Ws[16][64];
    __shared__ float Xs[16][64];
    const int n = blockIdx.z;
    const int o0 = blockIdx.y * 64;
    const int l0 = blockIdx.x * 64;
    const int t = threadIdx.x;
    const int lo = t & 63;        // o_local for W load, l_local for X load
    const int c4 = (t >> 6) * 4;  // 0,4,8,12
    const int tx = t & 15, ty = t >> 4;

    float acc[4][4];
    #pragma unroll
    for (int i = 0; i < 4; i++)
        #pragma unroll
        for (int j = 0; j < 4; j++) acc[i][j] = 0.f;

    const float* Wp = W + (size_t)(o0 + lo) * CCH;
    const float* Xp = X + (size_t)n * CCH * L + l0 + lo;

    for (int c0 = 0; c0 < CCH; c0 += 16) {
        float4 wv = *(const float4*)(Wp + c0 + c4);
        Ws[c4 + 0][lo] = wv.x; Ws[c4 + 1][lo] = wv.y;
        Ws[c4 + 2][lo] = wv.z; Ws[c4 + 3][lo] = wv.w;
        #pragma unroll
        for (int j = 0; j < 4; j++) Xs[c4 + j][lo] = Xp[(size_t)(c0 + c4 + j) * L];
        __syncthreads();
        #pragma unroll
        for (int cc = 0; cc < 16; cc++) {
            float4 a = *(const float4*)&Ws[cc][ty * 4];
            float4 x = *(const float4*)&Xs[cc][tx * 4];
            acc[0][0] += a.x * x.x; acc[0][1] += a.x * x.y; acc[0][2] += a.x * x.z; acc[0][3] += a.x * x.w;
            acc[1][0] += a.y * x.x; acc[1][1] += a.y * x.y; acc[1][2] += a.y * x.z; acc[1][3] += a.y * x.w;
            acc[2][0] += a.z * x.x; acc[2][1] += a.z * x.y; acc[2][2] += a.z * x.z; acc[2][3] += a.z * x.w;
            acc[3][0] += a.w * x.x; acc[3][1] += a.w * x.y; acc[3][2] += a.w * x.z; acc[3][3] += a.w * x.w;
        }
        __syncthreads();
    }

    #pragma unroll
    for (int i = 0; i < 4; i++) {
        int o = o0 + ty * 4 + i;
        float bb = b[o];
        size_t row = (size_t)n * CCH + o;
        float4 r;
        r.x = acc[i][0] + bb; r.y = acc[i][1] + bb; r.z = acc[i][2] + bb; r.w = acc[i][3] + bb;
        if (res) {
            float4 rr = *(const float4*)&res[row * L + l0 + tx * 4];
            r.x += rr.x; r.y += rr.y; r.z += rr.z; r.w += rr.w;
        }
        *(float4*)&Y[row * ldY + l0 + tx * 4] = r;
    }
}

// ---------------- attention ----------------
// grid (L/(256*LPT) [>=1], 64, 2), block 256. Each thread: LPT query tokens.
template <int LPT>
__global__ __launch_bounds__(256)
void attn_kernel(const float* __restrict__ qb, const float* __restrict__ kb,
                 const float* __restrict__ vb, float* __restrict__ attnb,
                 float* __restrict__ dsacc_slot, int L, int M) {
    __shared__ float kv[256][8];
    __shared__ float redbuf[4];
    const int h = blockIdx.y, n = blockIdx.z;
    const int t = threadIdx.x;
    const int l0 = blockIdx.x * 256 * LPT;
    const size_t qbase = ((size_t)n * CCH + h * 4) * L;
    const size_t kbase = ((size_t)n * CCH + h * 4) * M;

    float qv[LPT][4];
    bool act[LPT];
    #pragma unroll
    for (int j = 0; j < LPT; j++) {
        int l = l0 + j * 256 + t;
        act[j] = (l < L);
        #pragma unroll
        for (int d = 0; d < 4; d++)
            qv[j][d] = act[j] ? 0.5f * qb[qbase + (size_t)d * L + l] : 0.f;
    }
    float den[LPT], dst[LPT], ox[LPT], oy[LPT], oz[LPT], ow[LPT];
    #pragma unroll
    for (int j = 0; j < LPT; j++) { den[j] = 0.f; dst[j] = 0.f; ox[j] = oy[j] = oz[j] = ow[j] = 0.f; }

    for (int m0 = 0; m0 < M; m0 += 256) {
        int cnt = min(256, M - m0);
        if (t < cnt) {
            #pragma unroll
            for (int d = 0; d < 4; d++) kv[t][d] = kb[kbase + (size_t)d * M + m0 + t];
            #pragma unroll
            for (int d = 0; d < 4; d++) kv[t][4 + d] = vb[kbase + (size_t)d * M + m0 + t];
        }
        __syncthreads();
        if (m0 + 256 <= L) {
            // pure-spatial tile: no ds accounting
            #pragma unroll 8
            for (int m = 0; m < 256; m++) {
                float4 kk = *(const float4*)&kv[m][0];
                float4 vv = *(const float4*)&kv[m][4];
                #pragma unroll
                for (int j = 0; j < LPT; j++) {
                    float s = qv[j][0] * kk.x + qv[j][1] * kk.y + qv[j][2] * kk.z + qv[j][3] * kk.w;
                    float e = __expf(s);
                    den[j] += e;
                    ox[j] += e * vv.x; oy[j] += e * vv.y; oz[j] += e * vv.z; ow[j] += e * vv.w;
                }
            }
        } else {
            #pragma unroll 4
            for (int m = 0; m < cnt; m++) {
                float4 kk = *(const float4*)&kv[m][0];
                float4 vv = *(const float4*)&kv[m][4];
                float dsm = (m0 + m >= L) ? 1.f : 0.f;
                #pragma unroll
                for (int j = 0; j < LPT; j++) {
                    float s = qv[j][0] * kk.x + qv[j][1] * kk.y + qv[j][2] * kk.z + qv[j][3] * kk.w;
                    float e = __expf(s);
                    den[j] += e;
                    dst[j] += dsm * e;
                    ox[j] += e * vv.x; oy[j] += e * vv.y; oz[j] += e * vv.z; ow[j] += e * vv.w;
                }
            }
        }
        __syncthreads();
    }

    float total = 0.f;
    #pragma unroll
    for (int j = 0; j < LPT; j++) {
        if (!act[j]) continue;
        int l = l0 + j * 256 + t;
        float inv = 1.f / den[j];
        attnb[qbase + 0 * (size_t)L + l] = ox[j] * inv;
        attnb[qbase + 1 * (size_t)L + l] = oy[j] * inv;
        attnb[qbase + 2 * (size_t)L + l] = oz[j] * inv;
        attnb[qbase + 3 * (size_t)L + l] = ow[j] * inv;
        total += dst[j] * inv;
    }
    #pragma unroll
    for (int off = 32; off > 0; off >>= 1) total += __shfl_down(total, off);
    int wid = t >> 6;
    if ((t & 63) == 0) redbuf[wid] = total;
    __syncthreads();
    if (t == 0) atomicAdd(&dsacc_slot[n], redbuf[0] + redbuf[1] + redbuf[2] + redbuf[3]);
}

// ---------------- finalize ds ratios ----------------
__global__ void finalize_kernel(const float* __restrict__ dsacc, float* __restrict__ out) {
    int i = threadIdx.x;
    if (i < 8) {
        int lvl = i >> 1;
        int L = 4096 >> (2 * lvl);
        out[i] = dsacc[i] / (float)(HEADS * L);
    }
}

extern "C" void kernel_launch(void* const* d_in, const int* in_sizes, int n_in,
                              void* d_out, int out_size, void* d_ws, size_t ws_size,
                              hipStream_t stream) {
    const float* sp[4] = {(const float*)d_in[0], (const float*)d_in[1], (const float*)d_in[2], (const float*)d_in[3]};
    const float* iv[4] = {(const float*)d_in[4], (const float*)d_in[5], (const float*)d_in[6], (const float*)d_in[7]};
    const float* dd[4] = {(const float*)d_in[8], (const float*)d_in[9], (const float*)d_in[10], (const float*)d_in[11]};
    const float* Wq = (const float*)d_in[12];
    const float* bq = (const float*)d_in[13];
    const float* Wk = (const float*)d_in[14];
    const float* bk = (const float*)d_in[15];
    const float* Wv = (const float*)d_in[16];
    const float* bv = (const float*)d_in[17];
    const float* Wo = (const float*)d_in[18];
    const float* bo = (const float*)d_in[19];
    const float* Wdsk = (const float*)d_in[20];
    const float* bdsk = (const float*)d_in[21];
    const float* Wdsv = (const float*)d_in[22];
    const float* bdsv = (const float*)d_in[23];
    const float* gate = (const float*)d_in[24];

    float* ws = (float*)d_ws;
    float* pooled = ws + OFF_POOLED;
    float* qb = ws + OFF_Q;
    float* kb = ws + OFF_K;
    float* vb = ws + OFF_V;
    float* attnb = ws + OFF_ATTN;
    float* dsacc = ws + OFF_DSACC;
    float* out = (float*)d_out;

    hipMemsetAsync(dsacc, 0, 8 * sizeof(float), stream);

    pooled_kernel<<<dim3(256, 2, 4), 64, 0, stream>>>(dd[0], dd[1], dd[2], dd[3], pooled);
    dstok_kernel<<<dim3(32, 2, 4), 256, 0, stream>>>(Wdsk, bdsk, Wdsv, bdsv, gate, pooled, kb, vb);

    for (int i = 0; i < 4; i++) {
        int L = LVL_L[i], M = L + 32;
        dim3 grid(L / 64, 4, 2);
        conv_kernel<<<grid, 256, 0, stream>>>(sp[i], Wq + (size_t)i * 65536, bq + i * 256,
                                              qb + QOFF[i], nullptr, L, L);
        conv_kernel<<<grid, 256, 0, stream>>>(iv[i], Wk + (size_t)i * 65536, bk + i * 256,
                                              kb + KVOFF[i], nullptr, L, M);
        conv_kernel<<<grid, 256, 0, stream>>>(iv[i], Wv + (size_t)i * 65536, bv + i * 256,
                                              vb + KVOFF[i], nullptr, L, M);
    }

    for (int i = 0; i < 4; i++) {
        int L = LVL_L[i], M = L + 32;
        if (L >= 512) {
            // LPT=2 -> 512 l per block
            attn_kernel<2><<<dim3(L / 512, HEADS, 2), 256, 0, stream>>>(
                qb + QOFF[i], kb + KVOFF[i], vb + KVOFF[i], attnb + QOFF[i], dsacc + i * 2, L, M);
        } else {
            attn_kernel<1><<<dim3(1, HEADS, 2), 256, 0, stream>>>(
                qb + QOFF[i], kb + KVOFF[i], vb + KVOFF[i], attnb + QOFF[i], dsacc + i * 2, L, M);
        }
    }

    for (int i = 0; i < 4; i++) {
        int L = LVL_L[i];
        dim3 grid(L / 64, 4, 2);
        conv_kernel<<<grid, 256, 0, stream>>>(attnb + QOFF[i], Wo + (size_t)i * 65536, bo + i * 256,
                                              out + QOFF[i], sp[i], L, L);
    }

    finalize_kernel<<<1, 8, 0, stream>>>(dsacc, out + DS_OUT_OFF);
}

// Round 2
// 1016.578 us; speedup vs baseline: 1.3547x; 1.3547x over previous
//
#include <hip/hip_runtime.h>
#include <math.h>

#define CCH 256
#define NB 2
#define HEADS 64

typedef __bf16 bf16x8 __attribute__((ext_vector_type(8)));
typedef __bf16 bf16x4 __attribute__((ext_vector_type(4)));
typedef float f32x4 __attribute__((ext_vector_type(4)));

__device__ inline float fexp2(float x) {
#if __has_builtin(__builtin_amdgcn_exp2f)
    return __builtin_amdgcn_exp2f(x);
#else
    return exp2f(x);
#endif
}

// ---------------- workspace layout (float element offsets) ----------------
static const size_t OFF_POOLED = 0;
static const size_t OFF_Q      = 2048;
static const size_t OFF_K      = 2048 + 2785280;              // 2787328
static const size_t OFF_V      = 2787328 + 2850816;           // 5638144
static const size_t OFF_ATTN   = 5638144 + 2850816;           // 8488960
static const size_t OFF_DSACC  = 8488960 + 2785280;           // 11274240 (512 floats)

static const size_t QOFF[4]  = {0, 2097152, 2621440, 2752512};   // 512*prefix(L)
static const size_t KVOFF[4] = {0, 2113536, 2654208, 2801664};   // 512*prefix(M)
static const int    LVL_L[4] = {4096, 1024, 256, 64};
static const size_t DS_OUT_OFF = 2785280;

// ---------------- pooled = mean over H*W of ds ----------------
__global__ void pooled_kernel(const float* __restrict__ d0, const float* __restrict__ d1,
                              const float* __restrict__ d2, const float* __restrict__ d3,
                              float* __restrict__ pooled) {
    int c = blockIdx.x, n = blockIdx.y, lvl = blockIdx.z;
    int t = threadIdx.x;  // 0..63
    const float* d = (lvl == 0) ? d0 : (lvl == 1) ? d1 : (lvl == 2) ? d2 : d3;
    int L = 4096 >> (2 * lvl);
    const float* p = d + ((size_t)n * CCH + c) * L;
    float s = 0.f;
    for (int i = t; i < L; i += 64) s += p[i];
    #pragma unroll
    for (int off = 32; off > 0; off >>= 1) s += __shfl_down(s, off);
    if (t == 0) pooled[(lvl * NB + n) * CCH + c] = s / (float)L;
}

// ---------------- ds token GEMV ----------
__global__ __launch_bounds__(256)
void dstok_kernel(const float* __restrict__ Wdsk, const float* __restrict__ bdsk,
                  const float* __restrict__ Wdsv, const float* __restrict__ bdsv,
                  const float* __restrict__ ds_gate, const float* __restrict__ pooled,
                  float* __restrict__ kbuf, float* __restrict__ vbuf) {
    int lvl = blockIdx.z, n = blockIdx.y;
    int j = blockIdx.x * 256 + threadIdx.x;
    const float4* wk = (const float4*)(Wdsk + ((size_t)lvl * 8192 + j) * CCH);
    const float4* wv = (const float4*)(Wdsv + ((size_t)lvl * 8192 + j) * CCH);
    const float4* pp = (const float4*)(pooled + (size_t)(lvl * NB + n) * CCH);
    float ak = 0.f, av = 0.f;
    #pragma unroll 8
    for (int c4 = 0; c4 < CCH / 4; c4++) {
        float4 p = pp[c4], a = wk[c4], b = wv[c4];
        ak += a.x * p.x + a.y * p.y + a.z * p.z + a.w * p.w;
        av += b.x * p.x + b.y * p.y + b.z * p.z + b.w * p.w;
    }
    ak += bdsk[lvl * 8192 + j];
    av += bdsv[lvl * 8192 + j];
    float gate = 1.f / (1.f + __expf(-ds_gate[lvl]));
    av *= gate;
    int o = j >> 5, tk = j & 31;
    int L = 4096 >> (2 * lvl);
    int M = L + 32;
    size_t kvoff = KVOFF[0];
    if (lvl == 1) kvoff = 2113536; else if (lvl == 2) kvoff = 2654208; else if (lvl == 3) kvoff = 2801664;
    size_t idx = kvoff + ((size_t)(n * CCH + o)) * M + L + tk;
    kbuf[idx] = ak;
    vbuf[idx] = av;
}

// ---------------- conv1x1 GEMM ----------------
__global__ __launch_bounds__(256)
void conv_kernel(const float* __restrict__ X, const float* __restrict__ W,
                 const float* __restrict__ b, float* __restrict__ Y,
                 const float* __restrict__ res, int L, int ldY) {
    __shared__ float Ws[16][64];
    __shared__ float Xs[16][64];
    const int n = blockIdx.z;
    const int o0 = blockIdx.y * 64;
    const int l0 = blockIdx.x * 64;
    const int t = threadIdx.x;
    const int lo = t & 63;
    const int c4 = (t >> 6) * 4;
    const int tx = t & 15, ty = t >> 4;

    float acc[4][4];
    #pragma unroll
    for (int i = 0; i < 4; i++)
        #pragma unroll
        for (int j = 0; j < 4; j++) acc[i][j] = 0.f;

    const float* Wp = W + (size_t)(o0 + lo) * CCH;
    const float* Xp = X + (size_t)n * CCH * L + l0 + lo;

    for (int c0 = 0; c0 < CCH; c0 += 16) {
        float4 wv = *(const float4*)(Wp + c0 + c4);
        Ws[c4 + 0][lo] = wv.x; Ws[c4 + 1][lo] = wv.y;
        Ws[c4 + 2][lo] = wv.z; Ws[c4 + 3][lo] = wv.w;
        #pragma unroll
        for (int j = 0; j < 4; j++) Xs[c4 + j][lo] = Xp[(size_t)(c0 + c4 + j) * L];
        __syncthreads();
        #pragma unroll
        for (int cc = 0; cc < 16; cc++) {
            float4 a = *(const float4*)&Ws[cc][ty * 4];
            float4 x = *(const float4*)&Xs[cc][tx * 4];
            acc[0][0] += a.x * x.x; acc[0][1] += a.x * x.y; acc[0][2] += a.x * x.z; acc[0][3] += a.x * x.w;
            acc[1][0] += a.y * x.x; acc[1][1] += a.y * x.y; acc[1][2] += a.y * x.z; acc[1][3] += a.y * x.w;
            acc[2][0] += a.z * x.x; acc[2][1] += a.z * x.y; acc[2][2] += a.z * x.z; acc[2][3] += a.z * x.w;
            acc[3][0] += a.w * x.x; acc[3][1] += a.w * x.y; acc[3][2] += a.w * x.z; acc[3][3] += a.w * x.w;
        }
        __syncthreads();
    }

    #pragma unroll
    for (int i = 0; i < 4; i++) {
        int o = o0 + ty * 4 + i;
        float bb = b[o];
        size_t row = (size_t)n * CCH + o;
        float4 r;
        r.x = acc[i][0] + bb; r.y = acc[i][1] + bb; r.z = acc[i][2] + bb; r.w = acc[i][3] + bb;
        if (res) {
            float4 rr = *(const float4*)&res[row * L + l0 + tx * 4];
            r.x += rr.x; r.y += rr.y; r.z += rr.z; r.w += rr.w;
        }
        *(float4*)&Y[row * ldY + l0 + tx * 4] = r;
    }
}

// ---------------- MFMA attention ----------------
// Per wave: 8 Q-tiles of 16 l's. Per 32-key chunk:
//   S^T = K·Q via mfma_f32_16x16x32_bf16 (K-dim = head_dim 4, zero-padded)
//   w = exp2(S^T) (q pre-scaled by 0.5*log2e), packed bf16 -> LDS -> A-frag
//   PV via one K=32 MFMA; B has cols {v0..v3, ones, ds-indicator} so the
//   softmax denominator and ds-token mass fall out of the same accumulator.
__global__ __launch_bounds__(256)
void attn_mfma_kernel(const float* __restrict__ qb, const float* __restrict__ kb,
                      const float* __restrict__ vb, float* __restrict__ attnb,
                      float* __restrict__ dsacc_lvl, int L, int M) {
    __shared__ __align__(16) __bf16 wlds[4][16][40];   // [wave][l][m] row stride 80B
    const int h = blockIdx.y, b = blockIdx.z;
    const int t = threadIdx.x;
    const int w = t >> 6;
    const int lane = t & 63;
    const int quad = lane >> 4;
    const int n16 = lane & 15;
    const size_t qbase = ((size_t)b * CCH + h * 4) * (size_t)L;
    const size_t kbase = ((size_t)b * CCH + h * 4) * (size_t)M;
    const float QSCALE = 0.72134752f;  // 0.5 * log2(e)

    bf16x8 qf[8];
    f32x4 acc[8];
    int tl0[8];
    bool valid[8];
    #pragma unroll
    for (int i = 0; i < 8; i++) {
        int tile = blockIdx.x * 32 + i * 4 + w;
        tl0[i] = tile * 16;
        valid[i] = (tl0[i] < L);
        #pragma unroll
        for (int e = 0; e < 8; e++) qf[i][e] = (__bf16)0.f;
        acc[i][0] = 0.f; acc[i][1] = 0.f; acc[i][2] = 0.f; acc[i][3] = 0.f;
        if (valid[i] && quad == 0) {
            int l = tl0[i] + n16;
            #pragma unroll
            for (int d = 0; d < 4; d++)
                qf[i][d] = (__bf16)(qb[qbase + (size_t)d * L + l] * QSCALE);
        }
    }

    f32x4 zero; zero[0] = 0.f; zero[1] = 0.f; zero[2] = 0.f; zero[3] = 0.f;

    for (int m0 = 0; m0 < M; m0 += 32) {
        // K fragments (A of S^T): A[m=lane&15][k=d], two 16-m tiles
        bf16x8 kf0, kf1;
        #pragma unroll
        for (int e = 0; e < 8; e++) { kf0[e] = (__bf16)0.f; kf1[e] = (__bf16)0.f; }
        if (quad == 0) {
            int ma = m0 + n16, mb = m0 + 16 + n16;
            #pragma unroll
            for (int d = 0; d < 4; d++) {
                kf0[d] = (__bf16)kb[kbase + (size_t)d * M + ma];
                kf1[d] = (__bf16)kb[kbase + (size_t)d * M + mb];
            }
        }
        // V fragment (B of PV): B[k=m_local][n]; n<4 -> v rows, 4 -> ones, 5 -> indicator
        bf16x8 vf;
        {
            int mrow = m0 + quad * 8;
            if (n16 < 4) {
                const float* vp = vb + kbase + (size_t)n16 * M + mrow;
                float4 v0 = *(const float4*)vp;
                float4 v1 = *(const float4*)(vp + 4);
                vf[0] = (__bf16)v0.x; vf[1] = (__bf16)v0.y; vf[2] = (__bf16)v0.z; vf[3] = (__bf16)v0.w;
                vf[4] = (__bf16)v1.x; vf[5] = (__bf16)v1.y; vf[6] = (__bf16)v1.z; vf[7] = (__bf16)v1.w;
            } else {
                float c = (n16 == 4) ? 1.f : ((n16 == 5 && m0 >= L) ? 1.f : 0.f);
                #pragma unroll
                for (int e = 0; e < 8; e++) vf[e] = (__bf16)c;
            }
        }

        #pragma unroll
        for (int i = 0; i < 8; i++) {
            if (!valid[i]) continue;
            f32x4 s0 = __builtin_amdgcn_mfma_f32_16x16x32_bf16(kf0, qf[i], zero, 0, 0, 0);
            f32x4 s1 = __builtin_amdgcn_mfma_f32_16x16x32_bf16(kf1, qf[i], zero, 0, 0, 0);
            bf16x4 w0, w1;
            #pragma unroll
            for (int r = 0; r < 4; r++) {
                w0[r] = (__bf16)fexp2(s0[r]);
                w1[r] = (__bf16)fexp2(s1[r]);
            }
            // C-frag of S^T: col = l (lane&15), rows m = quad*4+r  -> w[l][m]
            *(bf16x4*)&wlds[w][n16][quad * 4]      = w0;
            *(bf16x4*)&wlds[w][n16][16 + quad * 4] = w1;
            // A-frag of PV: A[l=lane&15][k=m=quad*8+j]
            bf16x8 wf = *(bf16x8*)&wlds[w][n16][quad * 8];
            acc[i] = __builtin_amdgcn_mfma_f32_16x16x32_bf16(wf, vf, acc[i], 0, 0, 0);
        }
    }

    // epilogue: C-frag of PV: col n16 in {d0..d3, den, dst}, rows l = quad*4+r
    float dsr = 0.f;
    #pragma unroll
    for (int i = 0; i < 8; i++) {
        if (!valid[i]) continue;
        #pragma unroll
        for (int r = 0; r < 4; r++) {
            float den = __shfl(acc[i][r], (lane & 48) | 4, 64);
            float rcp = 1.f / den;
            int l = tl0[i] + quad * 4 + r;
            if (n16 < 4)
                attnb[qbase + (size_t)n16 * L + l] = acc[i][r] * rcp;
            if (n16 == 5) dsr += acc[i][r] * rcp;
        }
    }
    dsr += __shfl_xor(dsr, 16, 64);
    dsr += __shfl_xor(dsr, 32, 64);
    if (n16 == 5 && quad == 0) atomicAdd(dsacc_lvl + (size_t)b * 64 + h, dsr);
}

// ---------------- finalize ds ratios ----------------
__global__ void finalize_kernel(const float* __restrict__ dsacc, float* __restrict__ out) {
    int i = blockIdx.x;   // 0..7 = lvl*2+b
    int t = threadIdx.x;  // 0..63
    float v = dsacc[i * 64 + t];
    #pragma unroll
    for (int off = 32; off > 0; off >>= 1) v += __shfl_down(v, off);
    if (t == 0) {
        int lvl = i >> 1;
        int L = 4096 >> (2 * lvl);
        out[i] = v / (float)(HEADS * L);
    }
}

extern "C" void kernel_launch(void* const* d_in, const int* in_sizes, int n_in,
                              void* d_out, int out_size, void* d_ws, size_t ws_size,
                              hipStream_t stream) {
    const float* sp[4] = {(const float*)d_in[0], (const float*)d_in[1], (const float*)d_in[2], (const float*)d_in[3]};
    const float* iv[4] = {(const float*)d_in[4], (const float*)d_in[5], (const float*)d_in[6], (const float*)d_in[7]};
    const float* dd[4] = {(const float*)d_in[8], (const float*)d_in[9], (const float*)d_in[10], (const float*)d_in[11]};
    const float* Wq = (const float*)d_in[12];
    const float* bq = (const float*)d_in[13];
    const float* Wk = (const float*)d_in[14];
    const float* bk = (const float*)d_in[15];
    const float* Wv = (const float*)d_in[16];
    const float* bv = (const float*)d_in[17];
    const float* Wo = (const float*)d_in[18];
    const float* bo = (const float*)d_in[19];
    const float* Wdsk = (const float*)d_in[20];
    const float* bdsk = (const float*)d_in[21];
    const float* Wdsv = (const float*)d_in[22];
    const float* bdsv = (const float*)d_in[23];
    const float* gate = (const float*)d_in[24];

    float* ws = (float*)d_ws;
    float* pooled = ws + OFF_POOLED;
    float* qb = ws + OFF_Q;
    float* kb = ws + OFF_K;
    float* vb = ws + OFF_V;
    float* attnb = ws + OFF_ATTN;
    float* dsacc = ws + OFF_DSACC;
    float* out = (float*)d_out;

    hipMemsetAsync(dsacc, 0, 512 * sizeof(float), stream);

    pooled_kernel<<<dim3(256, 2, 4), 64, 0, stream>>>(dd[0], dd[1], dd[2], dd[3], pooled);
    dstok_kernel<<<dim3(32, 2, 4), 256, 0, stream>>>(Wdsk, bdsk, Wdsv, bdsv, gate, pooled, kb, vb);

    for (int i = 0; i < 4; i++) {
        int L = LVL_L[i], M = L + 32;
        dim3 grid(L / 64, 4, 2);
        conv_kernel<<<grid, 256, 0, stream>>>(sp[i], Wq + (size_t)i * 65536, bq + i * 256,
                                              qb + QOFF[i], nullptr, L, L);
        conv_kernel<<<grid, 256, 0, stream>>>(iv[i], Wk + (size_t)i * 65536, bk + i * 256,
                                              kb + KVOFF[i], nullptr, L, M);
        conv_kernel<<<grid, 256, 0, stream>>>(iv[i], Wv + (size_t)i * 65536, bv + i * 256,
                                              vb + KVOFF[i], nullptr, L, M);
    }

    for (int i = 0; i < 4; i++) {
        int L = LVL_L[i], M = L + 32;
        dim3 grid((L + 511) / 512, HEADS, 2);
        attn_mfma_kernel<<<grid, 256, 0, stream>>>(
            qb + QOFF[i], kb + KVOFF[i], vb + KVOFF[i], attnb + QOFF[i],
            dsacc + (size_t)i * 128, L, M);
    }

    for (int i = 0; i < 4; i++) {
        int L = LVL_L[i];
        dim3 grid(L / 64, 4, 2);
        conv_kernel<<<grid, 256, 0, stream>>>(attnb + QOFF[i], Wo + (size_t)i * 65536, bo + i * 256,
                                              out + QOFF[i], sp[i], L, L);
    }

    finalize_kernel<<<dim3(8), 64, 0, stream>>>(dsacc, out + DS_OUT_OFF);
}

// Round 3
// 979.232 us; speedup vs baseline: 1.4064x; 1.0381x over previous
//
#include <hip/hip_runtime.h>
#include <math.h>

#define CCH 256
#define NB 2
#define HEADS 64
#define QSCALE 0.72134752f   // 0.5 * log2(e), folded into q-conv epilogue

typedef _Float16 f16;
typedef _Float16 f16x8 __attribute__((ext_vector_type(8)));
typedef _Float16 f16x4 __attribute__((ext_vector_type(4)));
typedef _Float16 f16x2 __attribute__((ext_vector_type(2)));
typedef float f32x4 __attribute__((ext_vector_type(4)));

// ---------------- workspace layout ----------------
// fp32 region (float offsets): pooled 2048, dsacc 512  -> 10240 bytes
static const size_t OFF_POOLED = 0;
static const size_t OFF_DSACC  = 2048;
// f16 region (element offsets from byte 10240)
static const size_t H_Q   = 0;          // [n][256][L] per level, scaled by QSCALE
static const size_t H_K   = 2785280;    // [n][M][256] per level (m-major!)
static const size_t H_V   = 5636096;    // [n][256][M] per level (d-major)
static const size_t H_ATT = 8486912;    // [n][L][256] per level (o-conv input layout)
static const size_t H_SPT = 11272192;   // sp transposed [n][L][256]
static const size_t H_IVT = 14057472;   // inv transposed
static const size_t H_W   = 16842752;   // Wq,Wk,Wv,Wo f16, 262144 each

static const size_t QOFF[4]  = {0, 2097152, 2621440, 2752512};   // 512*prefix(L)
static const size_t KVOFF[4] = {0, 2113536, 2654208, 2801664};   // 512*prefix(M)
static const int    LVL_L[4] = {4096, 1024, 256, 64};
static const size_t DS_OUT_OFF = 2785280;

// ---------------- pooled = mean over H*W of ds ----------------
__global__ void pooled_kernel(const float* __restrict__ d0, const float* __restrict__ d1,
                              const float* __restrict__ d2, const float* __restrict__ d3,
                              float* __restrict__ pooled) {
    int c = blockIdx.x, n = blockIdx.y, lvl = blockIdx.z;
    int t = threadIdx.x;
    const float* d = (lvl == 0) ? d0 : (lvl == 1) ? d1 : (lvl == 2) ? d2 : d3;
    int L = 4096 >> (2 * lvl);
    const float* p = d + ((size_t)n * CCH + c) * L;
    float s = 0.f;
    for (int i = t; i < L; i += 64) s += p[i];
    #pragma unroll
    for (int off = 32; off > 0; off >>= 1) s += __shfl_down(s, off);
    if (t == 0) pooled[(lvl * NB + n) * CCH + c] = s / (float)L;
}

// ---------------- weight fp32 -> f16 convert ----------------
__global__ __launch_bounds__(256)
void wconv_kernel(const float* __restrict__ Wq, const float* __restrict__ Wk,
                  const float* __restrict__ Wv, const float* __restrict__ Wo,
                  f16* __restrict__ dst) {
    int setId = blockIdx.y;
    const float* src = (setId == 0) ? Wq : (setId == 1) ? Wk : (setId == 2) ? Wv : Wo;
    size_t i = ((size_t)blockIdx.x * 256 + threadIdx.x) * 4;
    float4 v = *(const float4*)(src + i);
    f16x4 o;
    o[0] = (f16)v.x; o[1] = (f16)v.y; o[2] = (f16)v.z; o[3] = (f16)v.w;
    *(f16x4*)(dst + (size_t)setId * 262144 + i) = o;
}

// ---------------- X [n][c][L] fp32 -> XT [n][l][256] f16 ----------------
__global__ __launch_bounds__(256)
void xpose_kernel(const float* __restrict__ X, f16* __restrict__ XT, int L) {
    __shared__ float tile[32][33];
    int n = blockIdx.z;
    int c0 = blockIdx.y * 32, l0 = blockIdx.x * 32;
    int tx = threadIdx.x & 31, ty = threadIdx.x >> 5;
    #pragma unroll
    for (int k = 0; k < 4; k++) {
        int c = c0 + ty + k * 8;
        tile[ty + k * 8][tx] = X[((size_t)n * CCH + c) * L + l0 + tx];
    }
    __syncthreads();
    #pragma unroll
    for (int k = 0; k < 4; k++) {
        int l = l0 + ty + k * 8;
        XT[((size_t)n * L + l) * CCH + c0 + tx] = (f16)tile[tx][ty + k * 8];
    }
}

// ---------------- ds token GEMV (both n per thread; W read once) ----------
__global__ __launch_bounds__(256)
void dstok_kernel(const float* __restrict__ Wdsk, const float* __restrict__ bdsk,
                  const float* __restrict__ Wdsv, const float* __restrict__ bdsv,
                  const float* __restrict__ ds_gate, const float* __restrict__ pooled,
                  f16* __restrict__ kF, f16* __restrict__ vF) {
    int lvl = blockIdx.y;
    int j = blockIdx.x * 256 + threadIdx.x;
    const float4* wk = (const float4*)(Wdsk + ((size_t)lvl * 8192 + j) * CCH);
    const float4* wv = (const float4*)(Wdsv + ((size_t)lvl * 8192 + j) * CCH);
    const float4* p0 = (const float4*)(pooled + (size_t)(lvl * NB + 0) * CCH);
    const float4* p1 = (const float4*)(pooled + (size_t)(lvl * NB + 1) * CCH);
    float ak0 = 0.f, ak1 = 0.f, av0 = 0.f, av1 = 0.f;
    #pragma unroll 8
    for (int c4 = 0; c4 < CCH / 4; c4++) {
        float4 a = wk[c4], b = wv[c4], pa = p0[c4], pb = p1[c4];
        ak0 += a.x * pa.x + a.y * pa.y + a.z * pa.z + a.w * pa.w;
        ak1 += a.x * pb.x + a.y * pb.y + a.z * pb.z + a.w * pb.w;
        av0 += b.x * pa.x + b.y * pa.y + b.z * pa.z + b.w * pa.w;
        av1 += b.x * pb.x + b.y * pb.y + b.z * pb.z + b.w * pb.w;
    }
    float bk_ = bdsk[lvl * 8192 + j], bv_ = bdsv[lvl * 8192 + j];
    float gate = 1.f / (1.f + __expf(-ds_gate[lvl]));
    ak0 += bk_; ak1 += bk_;
    av0 = (av0 + bv_) * gate; av1 = (av1 + bv_) * gate;
    int o = j >> 5, tk = j & 31;
    int L = 4096 >> (2 * lvl);
    int M = L + 32;
    size_t kvoff = (lvl == 0) ? 0 : (lvl == 1) ? 2113536 : (lvl == 2) ? 2654208 : 2801664;
    // k tail: [n][m][256]
    kF[kvoff + ((size_t)(0 * M + L + tk)) * CCH + o] = (f16)ak0;
    kF[kvoff + ((size_t)(1 * M + L + tk)) * CCH + o] = (f16)ak1;
    // v tail: [n][256][M]
    vF[kvoff + ((size_t)(0 * CCH + o)) * M + L + tk] = (f16)av0;
    vF[kvoff + ((size_t)(1 * CCH + o)) * M + L + tk] = (f16)av1;
}

// ---------------- conv1x1 via f16 MFMA ----------------
// Y[n,o,l] = sum_c W[o,c] X[n,c,l] + b[o]; XT is [n][l][256] f16.
// Block: 256 thr = 4 waves; tile 64o x 128l (wave: 64o x 32l = 4x2 frags).
// MODE 0: f16 out [n][o][ld] with out_scale; MODE 1: f16 out m-major [n][ld][256];
// MODE 2: fp32 out + residual.
template <int MODE>
__global__ __launch_bounds__(256)
void conv_mfma_kernel(const f16* __restrict__ XT, const f16* __restrict__ Wf,
                      const float* __restrict__ bias,
                      f16* __restrict__ Yh, float* __restrict__ Yf,
                      const float* __restrict__ resid,
                      int L, int ld, float out_scale) {
    const int n = blockIdx.z;
    const int ob = blockIdx.y * 64;
    const int lb = blockIdx.x * 128;
    const int t = threadIdx.x, w = t >> 6, lane = t & 63;
    const int quad = lane >> 4, n16 = lane & 15;
    const int l0w = lb + w * 32;
    if (l0w >= L) return;

    f32x4 acc[4][2];
    #pragma unroll
    for (int f = 0; f < 4; f++)
        #pragma unroll
        for (int g = 0; g < 2; g++) { acc[f][g][0] = 0.f; acc[f][g][1] = 0.f; acc[f][g][2] = 0.f; acc[f][g][3] = 0.f; }

    const f16* xp = XT + ((size_t)n * L + l0w + n16) * CCH + quad * 8;
    const f16* wp = Wf + ((size_t)(ob + n16)) * CCH + quad * 8;

    #pragma unroll
    for (int c0 = 0; c0 < 256; c0 += 32) {
        f16x8 af[4], bf[2];
        #pragma unroll
        for (int f = 0; f < 4; f++) af[f] = *(const f16x8*)(wp + (size_t)f * 16 * CCH + c0);
        #pragma unroll
        for (int g = 0; g < 2; g++) bf[g] = *(const f16x8*)(xp + (size_t)g * 16 * CCH + c0);
        #pragma unroll
        for (int f = 0; f < 4; f++)
            #pragma unroll
            for (int g = 0; g < 2; g++)
                acc[f][g] = __builtin_amdgcn_mfma_f32_16x16x32_f16(af[f], bf[g], acc[f][g], 0, 0, 0);
    }

    #pragma unroll
    for (int f = 0; f < 4; f++) {
        #pragma unroll
        for (int g = 0; g < 2; g++) {
            int lloc = l0w + g * 16 + n16;
            float vals[4];
            #pragma unroll
            for (int r = 0; r < 4; r++)
                vals[r] = acc[f][g][r] + bias[ob + f * 16 + quad * 4 + r];
            if (MODE == 0) {
                #pragma unroll
                for (int r = 0; r < 4; r++)
                    Yh[((size_t)n * CCH + ob + f * 16 + quad * 4 + r) * (size_t)ld + lloc] =
                        (f16)(vals[r] * out_scale);
            } else if (MODE == 1) {
                f16x4 pk;
                #pragma unroll
                for (int r = 0; r < 4; r++) pk[r] = (f16)vals[r];
                *(f16x4*)(Yh + ((size_t)n * ld + lloc) * CCH + ob + f * 16 + quad * 4) = pk;
            } else {
                #pragma unroll
                for (int r = 0; r < 4; r++) {
                    size_t idx = ((size_t)n * CCH + ob + f * 16 + quad * 4 + r) * (size_t)ld + lloc;
                    Yf[idx] = vals[r] + resid[idx];
                }
            }
        }
    }
}

// ---------------- packed-f16 exp2 polynomial ----------------
__device__ inline f16x2 pk2(float a, float b) {
    auto r = __builtin_amdgcn_cvt_pkrtz(a, b);
    return *(f16x2*)&r;
}
#define SP2(v) f16x2{(f16)(v), (f16)(v)}
__device__ inline f16x2 exp2_pk(f16x2 x) {
    f16x2 p = SP2(1.540353e-4f);
    p = p * x + SP2(1.333356e-3f);
    p = p * x + SP2(9.618129e-3f);
    p = p * x + SP2(5.550411e-2f);
    p = p * x + SP2(2.402265e-1f);
    p = p * x + SP2(6.931472e-1f);
    p = p * x + SP2(1.0f);
    return p;
}
__device__ inline float clmp(float x) { return fminf(fmaxf(x, -2.75f), 2.75f); }  // v_med3

// ---------------- MFMA attention, no LDS (perm trick), f16, poly exp ------
// q: [n][256][L] (pre-scaled), kT: [n][M][256], v: [n][256][M], out: attT [n][L][256]
__global__ __launch_bounds__(256)
void attn_f16_kernel(const f16* __restrict__ qb, const f16* __restrict__ kT,
                     const f16* __restrict__ vb, f16* __restrict__ attT,
                     float* __restrict__ dsacc_lvl, int L, int M) {
    const int h = blockIdx.y, b = blockIdx.z;
    const int t = threadIdx.x, w = t >> 6, lane = t & 63;
    const int quad = lane >> 4, n16 = lane & 15;
    const size_t qbase = ((size_t)b * CCH + h * 4) * (size_t)L;
    const int mperm = ((n16 & 12) << 1) + (n16 & 3);  // (n16>>2)*8 + (n16&3)

    f16x8 qf[8];
    f32x4 acc[8];
    int tl0[8];
    bool valid[8];
    #pragma unroll
    for (int i = 0; i < 8; i++) {
        int tile = blockIdx.x * 32 + i * 4 + w;
        tl0[i] = tile * 16;
        valid[i] = (tl0[i] < L);
        #pragma unroll
        for (int e = 0; e < 8; e++) qf[i][e] = (f16)0.f;
        acc[i][0] = 0.f; acc[i][1] = 0.f; acc[i][2] = 0.f; acc[i][3] = 0.f;
        if (valid[i] && quad == 0) {
            int l = tl0[i] + n16;
            #pragma unroll
            for (int d = 0; d < 4; d++) qf[i][d] = qb[qbase + (size_t)d * L + l];
        }
    }

    const f16* kp = kT + ((size_t)b * M) * CCH + h * 4;         // + m*256
    const f16* vp = vb + ((size_t)b * CCH + h * 4 + (n16 & 3)) * (size_t)M;

    f32x4 zero; zero[0] = 0.f; zero[1] = 0.f; zero[2] = 0.f; zero[3] = 0.f;

    for (int m0 = 0; m0 < M; m0 += 32) {
        // A-operand of S^T: rows hold k at permuted m so C-frag == PV A-frag
        f16x8 kf0, kf1;
        #pragma unroll
        for (int e = 0; e < 8; e++) { kf0[e] = (f16)0.f; kf1[e] = (f16)0.f; }
        if (quad == 0) {
            f16x4 ka = *(const f16x4*)(kp + (size_t)(m0 + mperm) * CCH);
            f16x4 kb4 = *(const f16x4*)(kp + (size_t)(m0 + mperm + 4) * CCH);
            #pragma unroll
            for (int d = 0; d < 4; d++) { kf0[d] = ka[d]; kf1[d] = kb4[d]; }
        }
        // B of PV: cols {v0..v3, ones, ds-indicator, 0...}
        f16x8 vf;
        if (n16 < 4) {
            vf = *(const f16x8*)(vp + m0 + quad * 8);
        } else {
            f16 c = (f16)((n16 == 4) ? 1.f : ((n16 == 5 && m0 >= L) ? 1.f : 0.f));
            #pragma unroll
            for (int e = 0; e < 8; e++) vf[e] = c;
        }

        #pragma unroll
        for (int i = 0; i < 8; i++) {
            if (!valid[i]) continue;
            f32x4 s0 = __builtin_amdgcn_mfma_f32_16x16x32_f16(kf0, qf[i], zero, 0, 0, 0);
            f32x4 s1 = __builtin_amdgcn_mfma_f32_16x16x32_f16(kf1, qf[i], zero, 0, 0, 0);
            f16x2 e0 = exp2_pk(pk2(clmp(s0[0]), clmp(s0[1])));
            f16x2 e1 = exp2_pk(pk2(clmp(s0[2]), clmp(s0[3])));
            f16x2 e2 = exp2_pk(pk2(clmp(s1[0]), clmp(s1[1])));
            f16x2 e3 = exp2_pk(pk2(clmp(s1[2]), clmp(s1[3])));
            f16x8 wf;
            wf[0] = e0[0]; wf[1] = e0[1]; wf[2] = e1[0]; wf[3] = e1[1];
            wf[4] = e2[0]; wf[5] = e2[1]; wf[6] = e3[0]; wf[7] = e3[1];
            acc[i] = __builtin_amdgcn_mfma_f32_16x16x32_f16(wf, vf, acc[i], 0, 0, 0);
        }
    }

    // epilogue: C of PV: col n16 in {d0..d3, den, dst}, rows l = quad*4+r
    float dsr = 0.f;
    #pragma unroll
    for (int i = 0; i < 8; i++) {
        if (!valid[i]) continue;
        #pragma unroll
        for (int r = 0; r < 4; r++) {
            float den = __shfl(acc[i][r], (lane & 48) | 4, 64);
            float rcp = 1.f / den;
            int l = tl0[i] + quad * 4 + r;
            if (n16 < 4)
                attT[((size_t)b * L + l) * CCH + h * 4 + n16] = (f16)(acc[i][r] * rcp);
            if (n16 == 5) dsr += acc[i][r] * rcp;
        }
    }
    dsr += __shfl_xor(dsr, 16, 64);
    dsr += __shfl_xor(dsr, 32, 64);
    if (n16 == 5 && quad == 0) atomicAdd(dsacc_lvl + (size_t)b * 64 + h, dsr);
}

// ---------------- finalize ds ratios ----------------
__global__ void finalize_kernel(const float* __restrict__ dsacc, float* __restrict__ out) {
    int i = blockIdx.x;   // 0..7 = lvl*2+b
    int t = threadIdx.x;
    float v = dsacc[i * 64 + t];
    #pragma unroll
    for (int off = 32; off > 0; off >>= 1) v += __shfl_down(v, off);
    if (t == 0) {
        int lvl = i >> 1;
        int L = 4096 >> (2 * lvl);
        out[i] = v / (float)(HEADS * L);
    }
}

extern "C" void kernel_launch(void* const* d_in, const int* in_sizes, int n_in,
                              void* d_out, int out_size, void* d_ws, size_t ws_size,
                              hipStream_t stream) {
    const float* sp[4] = {(const float*)d_in[0], (const float*)d_in[1], (const float*)d_in[2], (const float*)d_in[3]};
    const float* iv[4] = {(const float*)d_in[4], (const float*)d_in[5], (const float*)d_in[6], (const float*)d_in[7]};
    const float* dd[4] = {(const float*)d_in[8], (const float*)d_in[9], (const float*)d_in[10], (const float*)d_in[11]};
    const float* Wq = (const float*)d_in[12];
    const float* bq = (const float*)d_in[13];
    const float* Wk = (const float*)d_in[14];
    const float* bk = (const float*)d_in[15];
    const float* Wv = (const float*)d_in[16];
    const float* bv = (const float*)d_in[17];
    const float* Wo = (const float*)d_in[18];
    const float* bo = (const float*)d_in[19];
    const float* Wdsk = (const float*)d_in[20];
    const float* bdsk = (const float*)d_in[21];
    const float* Wdsv = (const float*)d_in[22];
    const float* bdsv = (const float*)d_in[23];
    const float* gate = (const float*)d_in[24];

    float* ws = (float*)d_ws;
    float* pooled = ws + OFF_POOLED;
    float* dsacc = ws + OFF_DSACC;
    f16* hb = (f16*)((char*)d_ws + 10240);
    f16* qF   = hb + H_Q;
    f16* kF   = hb + H_K;
    f16* vF   = hb + H_V;
    f16* attF = hb + H_ATT;
    f16* spT  = hb + H_SPT;
    f16* ivT  = hb + H_IVT;
    f16* WF   = hb + H_W;   // q,k,v,o sets of 262144
    float* out = (float*)d_out;

    hipMemsetAsync(dsacc, 0, 512 * sizeof(float), stream);

    pooled_kernel<<<dim3(256, 2, 4), 64, 0, stream>>>(dd[0], dd[1], dd[2], dd[3], pooled);
    wconv_kernel<<<dim3(256, 4), 256, 0, stream>>>(Wq, Wk, Wv, Wo, WF);
    for (int i = 0; i < 4; i++) {
        int L = LVL_L[i];
        dim3 g(L / 32, 8, 2);
        xpose_kernel<<<g, 256, 0, stream>>>(sp[i], spT + QOFF[i], L);
        xpose_kernel<<<g, 256, 0, stream>>>(iv[i], ivT + QOFF[i], L);
    }
    dstok_kernel<<<dim3(32, 4), 256, 0, stream>>>(Wdsk, bdsk, Wdsv, bdsv, gate, pooled, kF, vF);

    for (int i = 0; i < 4; i++) {
        int L = LVL_L[i], M = L + 32;
        dim3 grid((L + 127) / 128, 4, 2);
        conv_mfma_kernel<0><<<grid, 256, 0, stream>>>(spT + QOFF[i], WF + 0 * 262144 + i * 65536,
                                                      bq + i * 256, qF + QOFF[i], nullptr, nullptr,
                                                      L, L, QSCALE);
        conv_mfma_kernel<1><<<grid, 256, 0, stream>>>(ivT + QOFF[i], WF + 1 * 262144 + i * 65536,
                                                      bk + i * 256, kF + KVOFF[i], nullptr, nullptr,
                                                      L, M, 1.f);
        conv_mfma_kernel<0><<<grid, 256, 0, stream>>>(ivT + QOFF[i], WF + 2 * 262144 + i * 65536,
                                                      bv + i * 256, vF + KVOFF[i], nullptr, nullptr,
                                                      L, M, 1.f);
    }

    for (int i = 0; i < 4; i++) {
        int L = LVL_L[i], M = L + 32;
        dim3 grid((L + 511) / 512, HEADS, 2);
        attn_f16_kernel<<<grid, 256, 0, stream>>>(qF + QOFF[i], kF + KVOFF[i], vF + KVOFF[i],
                                                  attF + QOFF[i], dsacc + (size_t)i * 128, L, M);
    }

    for (int i = 0; i < 4; i++) {
        int L = LVL_L[i];
        dim3 grid((L + 127) / 128, 4, 2);
        conv_mfma_kernel<2><<<grid, 256, 0, stream>>>(attF + QOFF[i], WF + 3 * 262144 + i * 65536,
                                                      bo + i * 256, nullptr, out + QOFF[i], sp[i],
                                                      L, L, 1.f);
    }

    finalize_kernel<<<dim3(8), 64, 0, stream>>>(dsacc, out + DS_OUT_OFF);
}

// Round 4
// 640.593 us; speedup vs baseline: 2.1498x; 1.5286x over previous
//
#include <hip/hip_runtime.h>
#include <math.h>

#define CCH 256
#define NB 2
#define HEADS 64
// Schraudolph-in-MFMA: q scaled by 1024*0.5*log2(e); QK accumulator C-init = magic.
#define QK_SCALE (0.72134752f * 1024.0f)
#define SCH_MAGIC 15316.0f   // 15360 - 44 (centers the +-3% secant error)

typedef _Float16 f16;
typedef _Float16 f16x8 __attribute__((ext_vector_type(8)));
typedef _Float16 f16x4 __attribute__((ext_vector_type(4)));
typedef float f32x4 __attribute__((ext_vector_type(4)));

// ---------------- workspace layout ----------------
static const size_t OFF_POOLED = 0;     // float offsets
static const size_t OFF_DSACC  = 2048;
// f16 region (element offsets from byte 10240)
static const size_t H_Q   = 0;          // [n][256][L], scaled by QK_SCALE
static const size_t H_K   = 2785280;    // [n][M][256] (m-major)
static const size_t H_V   = 5636096;    // [n][256][M]
static const size_t H_ATT = 8486912;    // [n][L][256]
static const size_t H_SPT = 11272192;   // sp transposed [n][l][256]
static const size_t H_IVT = 14057472;   // inv transposed
static const size_t H_W   = 16842752;   // Wq,Wk,Wv,Wo f16, 262144 each

static const size_t DS_OUT_OFF = 2785280;

// device-side level tables
__device__ __forceinline__ void lvl_tables(int lvl, int& L, int& M, size_t& qo, size_t& kvo) {
    const int Ls[4] = {4096, 1024, 256, 64};
    const size_t qoff[4] = {0, 2097152, 2621440, 2752512};
    const size_t kvoff[4] = {0, 2113536, 2654208, 2801664};
    L = Ls[lvl]; M = L + 32; qo = qoff[lvl]; kvo = kvoff[lvl];
}

struct P8 { const float* a[8]; };

// ---------------- pooled = mean over H*W of ds ----------------
__global__ void pooled_kernel(const float* __restrict__ d0, const float* __restrict__ d1,
                              const float* __restrict__ d2, const float* __restrict__ d3,
                              float* __restrict__ pooled) {
    int c = blockIdx.x, n = blockIdx.y, lvl = blockIdx.z;
    int t = threadIdx.x;
    const float* d = (lvl == 0) ? d0 : (lvl == 1) ? d1 : (lvl == 2) ? d2 : d3;
    int L = 4096 >> (2 * lvl);
    const float* p = d + ((size_t)n * CCH + c) * L;
    float s = 0.f;
    for (int i = t; i < L; i += 64) s += p[i];
    #pragma unroll
    for (int off = 32; off > 0; off >>= 1) s += __shfl_down(s, off);
    if (t == 0) pooled[(lvl * NB + n) * CCH + c] = s / (float)L;
}

// ---------------- weight fp32 -> f16 convert ----------------
__global__ __launch_bounds__(256)
void wconv_kernel(const float* __restrict__ Wq, const float* __restrict__ Wk,
                  const float* __restrict__ Wv, const float* __restrict__ Wo,
                  f16* __restrict__ dst) {
    int setId = blockIdx.y;
    const float* src = (setId == 0) ? Wq : (setId == 1) ? Wk : (setId == 2) ? Wv : Wo;
    size_t i = ((size_t)blockIdx.x * 256 + threadIdx.x) * 4;
    float4 v = *(const float4*)(src + i);
    f16x4 o;
    o[0] = (f16)v.x; o[1] = (f16)v.y; o[2] = (f16)v.z; o[3] = (f16)v.w;
    *(f16x4*)(dst + (size_t)setId * 262144 + i) = o;
}

// ---------------- all transposes in one dispatch ----------------
// grid (170, 8, 4): x -> (lvl, l-block), y -> c-block, z -> src*2+n
__global__ __launch_bounds__(256)
void xpose_all_kernel(P8 ptrs, f16* __restrict__ spT, f16* __restrict__ ivT) {
    __shared__ float tile[32][33];
    int x = blockIdx.x, lvl, xl;
    if (x < 128) { lvl = 0; xl = x; }
    else if (x < 160) { lvl = 1; xl = x - 128; }
    else if (x < 168) { lvl = 2; xl = x - 160; }
    else { lvl = 3; xl = x - 168; }
    int L, M; size_t qo, kvo;
    lvl_tables(lvl, L, M, qo, kvo);
    int src = blockIdx.z >> 1, n = blockIdx.z & 1;
    const float* X = ptrs.a[src * 4 + lvl];
    f16* XT = (src == 0 ? spT : ivT) + qo;
    int c0 = blockIdx.y * 32, l0 = xl * 32;
    int tx = threadIdx.x & 31, ty = threadIdx.x >> 5;
    #pragma unroll
    for (int k = 0; k < 4; k++) {
        int c = c0 + ty + k * 8;
        tile[ty + k * 8][tx] = X[((size_t)n * CCH + c) * L + l0 + tx];
    }
    __syncthreads();
    #pragma unroll
    for (int k = 0; k < 4; k++) {
        int l = l0 + ty + k * 8;
        XT[((size_t)n * L + l) * CCH + c0 + tx] = (f16)tile[tx][ty + k * 8];
    }
}

// ---------------- ds token GEMV: 2 threads per j (c halves), shfl combine ---
__global__ __launch_bounds__(256)
void dstok_kernel(const float* __restrict__ Wdsk, const float* __restrict__ bdsk,
                  const float* __restrict__ Wdsv, const float* __restrict__ bdsv,
                  const float* __restrict__ ds_gate, const float* __restrict__ pooled,
                  f16* __restrict__ kF, f16* __restrict__ vF) {
    int lvl = blockIdx.y;
    int t = threadIdx.x;
    int j = blockIdx.x * 128 + (t >> 1);
    int half = t & 1;
    const float4* wk = (const float4*)(Wdsk + ((size_t)lvl * 8192 + j) * CCH) + half * 32;
    const float4* wv = (const float4*)(Wdsv + ((size_t)lvl * 8192 + j) * CCH) + half * 32;
    const float4* p0 = (const float4*)(pooled + (size_t)(lvl * NB + 0) * CCH) + half * 32;
    const float4* p1 = (const float4*)(pooled + (size_t)(lvl * NB + 1) * CCH) + half * 32;
    float ak0 = 0.f, ak1 = 0.f, av0 = 0.f, av1 = 0.f;
    #pragma unroll 8
    for (int c4 = 0; c4 < 32; c4++) {
        float4 a = wk[c4], b = wv[c4], pa = p0[c4], pb = p1[c4];
        ak0 += a.x * pa.x + a.y * pa.y + a.z * pa.z + a.w * pa.w;
        ak1 += a.x * pb.x + a.y * pb.y + a.z * pb.z + a.w * pb.w;
        av0 += b.x * pa.x + b.y * pa.y + b.z * pa.z + b.w * pa.w;
        av1 += b.x * pb.x + b.y * pb.y + b.z * pb.z + b.w * pb.w;
    }
    ak0 += __shfl_xor(ak0, 1); ak1 += __shfl_xor(ak1, 1);
    av0 += __shfl_xor(av0, 1); av1 += __shfl_xor(av1, 1);
    if (half) return;
    float bk_ = bdsk[lvl * 8192 + j], bv_ = bdsv[lvl * 8192 + j];
    float gate = 1.f / (1.f + __expf(-ds_gate[lvl]));
    ak0 += bk_; ak1 += bk_;
    av0 = (av0 + bv_) * gate; av1 = (av1 + bv_) * gate;
    int o = j >> 5, tk = j & 31;
    int L, M; size_t qo, kvo;
    lvl_tables(lvl, L, M, qo, kvo);
    kF[kvo + ((size_t)(0 * M + L + tk)) * CCH + o] = (f16)ak0;
    kF[kvo + ((size_t)(1 * M + L + tk)) * CCH + o] = (f16)ak1;
    vF[kvo + ((size_t)(0 * CCH + o)) * M + L + tk] = (f16)av0;
    vF[kvo + ((size_t)(1 * CCH + o)) * M + L + tk] = (f16)av1;
}

// ---------------- fused q/k/v conv1x1 via f16 MFMA, all levels ------------
// grid (43, 12, 2): x -> (lvl, l-block of 128); y: type = y>>2, ob = (y&3)*64; z = n
__global__ __launch_bounds__(256)
void convqkv_kernel(const f16* __restrict__ spT, const f16* __restrict__ ivT,
                    const f16* __restrict__ WF,
                    const float* __restrict__ bq, const float* __restrict__ bk,
                    const float* __restrict__ bv,
                    f16* __restrict__ qF, f16* __restrict__ kF, f16* __restrict__ vF) {
    int x = blockIdx.x, lvl, xl;
    if (x < 32) { lvl = 0; xl = x; }
    else if (x < 40) { lvl = 1; xl = x - 32; }
    else if (x < 42) { lvl = 2; xl = x - 40; }
    else { lvl = 3; xl = x - 42; }
    int L, M; size_t qo, kvo;
    lvl_tables(lvl, L, M, qo, kvo);
    const int type = blockIdx.y >> 2;
    const int ob = (blockIdx.y & 3) * 64;
    const int n = blockIdx.z;
    const int t = threadIdx.x, w = t >> 6, lane = t & 63;
    const int quad = lane >> 4, n16 = lane & 15;
    const int l0w = xl * 128 + w * 32;
    if (l0w >= L) return;

    const f16* XT = ((type == 0) ? spT : ivT) + qo;
    const f16* Wf = WF + (size_t)type * 262144 + (size_t)lvl * 65536;
    const float* bias = ((type == 0) ? bq : (type == 1) ? bk : bv) + lvl * 256;

    f32x4 acc[4][2];
    #pragma unroll
    for (int f = 0; f < 4; f++)
        #pragma unroll
        for (int g = 0; g < 2; g++) { acc[f][g][0]=0.f; acc[f][g][1]=0.f; acc[f][g][2]=0.f; acc[f][g][3]=0.f; }

    const f16* xp = XT + ((size_t)n * L + l0w + n16) * CCH + quad * 8;
    const f16* wp = Wf + ((size_t)(ob + n16)) * CCH + quad * 8;

    #pragma unroll
    for (int c0 = 0; c0 < 256; c0 += 32) {
        f16x8 af[4], bf[2];
        #pragma unroll
        for (int f = 0; f < 4; f++) af[f] = *(const f16x8*)(wp + (size_t)f * 16 * CCH + c0);
        #pragma unroll
        for (int g = 0; g < 2; g++) bf[g] = *(const f16x8*)(xp + (size_t)g * 16 * CCH + c0);
        #pragma unroll
        for (int f = 0; f < 4; f++)
            #pragma unroll
            for (int g = 0; g < 2; g++)
                acc[f][g] = __builtin_amdgcn_mfma_f32_16x16x32_f16(af[f], bf[g], acc[f][g], 0, 0, 0);
    }

    #pragma unroll
    for (int f = 0; f < 4; f++) {
        #pragma unroll
        for (int g = 0; g < 2; g++) {
            int lloc = l0w + g * 16 + n16;
            float vals[4];
            #pragma unroll
            for (int r = 0; r < 4; r++)
                vals[r] = acc[f][g][r] + bias[ob + f * 16 + quad * 4 + r];
            if (type == 0) {           // q: [n][c][L], scaled
                #pragma unroll
                for (int r = 0; r < 4; r++)
                    qF[qo + ((size_t)n * CCH + ob + f * 16 + quad * 4 + r) * (size_t)L + lloc] =
                        (f16)(vals[r] * QK_SCALE);
            } else if (type == 1) {    // k: [n][m][256]
                f16x4 pk;
                #pragma unroll
                for (int r = 0; r < 4; r++) pk[r] = (f16)vals[r];
                *(f16x4*)(kF + kvo + ((size_t)n * M + lloc) * CCH + ob + f * 16 + quad * 4) = pk;
            } else {                   // v: [n][c][M]
                #pragma unroll
                for (int r = 0; r < 4; r++)
                    vF[kvo + ((size_t)n * CCH + ob + f * 16 + quad * 4 + r) * (size_t)M + lloc] =
                        (f16)vals[r];
            }
        }
    }
}

// ---------------- o-conv (fp32 out + residual), all levels ----------------
__global__ __launch_bounds__(256)
void convo_kernel(const f16* __restrict__ attT, const f16* __restrict__ WF,
                  const float* __restrict__ bo, const float* __restrict__ s0,
                  const float* __restrict__ s1, const float* __restrict__ s2,
                  const float* __restrict__ s3, float* __restrict__ out) {
    int x = blockIdx.x, lvl, xl;
    if (x < 32) { lvl = 0; xl = x; }
    else if (x < 40) { lvl = 1; xl = x - 32; }
    else if (x < 42) { lvl = 2; xl = x - 40; }
    else { lvl = 3; xl = x - 42; }
    int L, M; size_t qo, kvo;
    lvl_tables(lvl, L, M, qo, kvo);
    const float* resid = (lvl == 0) ? s0 : (lvl == 1) ? s1 : (lvl == 2) ? s2 : s3;
    const int ob = blockIdx.y * 64;
    const int n = blockIdx.z;
    const int t = threadIdx.x, w = t >> 6, lane = t & 63;
    const int quad = lane >> 4, n16 = lane & 15;
    const int l0w = xl * 128 + w * 32;
    if (l0w >= L) return;

    const f16* Wf = WF + 3 * 262144 + (size_t)lvl * 65536;
    const float* bias = bo + lvl * 256;

    f32x4 acc[4][2];
    #pragma unroll
    for (int f = 0; f < 4; f++)
        #pragma unroll
        for (int g = 0; g < 2; g++) { acc[f][g][0]=0.f; acc[f][g][1]=0.f; acc[f][g][2]=0.f; acc[f][g][3]=0.f; }

    const f16* xp = attT + qo + ((size_t)n * L + l0w + n16) * CCH + quad * 8;
    const f16* wp = Wf + ((size_t)(ob + n16)) * CCH + quad * 8;

    #pragma unroll
    for (int c0 = 0; c0 < 256; c0 += 32) {
        f16x8 af[4], bf[2];
        #pragma unroll
        for (int f = 0; f < 4; f++) af[f] = *(const f16x8*)(wp + (size_t)f * 16 * CCH + c0);
        #pragma unroll
        for (int g = 0; g < 2; g++) bf[g] = *(const f16x8*)(xp + (size_t)g * 16 * CCH + c0);
        #pragma unroll
        for (int f = 0; f < 4; f++)
            #pragma unroll
            for (int g = 0; g < 2; g++)
                acc[f][g] = __builtin_amdgcn_mfma_f32_16x16x32_f16(af[f], bf[g], acc[f][g], 0, 0, 0);
    }

    #pragma unroll
    for (int f = 0; f < 4; f++) {
        #pragma unroll
        for (int g = 0; g < 2; g++) {
            int lloc = l0w + g * 16 + n16;
            #pragma unroll
            for (int r = 0; r < 4; r++) {
                size_t idx = qo + ((size_t)n * CCH + ob + f * 16 + quad * 4 + r) * (size_t)L + lloc;
                out[idx] = acc[f][g][r] + bias[ob + f * 16 + quad * 4 + r] + resid[idx - qo];
            }
        }
    }
}

// ---------------- MFMA attention, Schraudolph exp folded into MFMA --------
// grid (12, 64, 2): x -> (lvl, l-block of 512); y = h; z = b
__global__ __launch_bounds__(256)
void attn_all_kernel(const f16* __restrict__ qBase, const f16* __restrict__ kBase,
                     const f16* __restrict__ vBase, f16* __restrict__ attBase,
                     float* __restrict__ dsacc) {
    int x = blockIdx.x, lvl, xl;
    if (x < 8) { lvl = 0; xl = x; }
    else if (x < 10) { lvl = 1; xl = x - 8; }
    else if (x < 11) { lvl = 2; xl = x - 10; }
    else { lvl = 3; xl = x - 11; }
    int L, M; size_t qo, kvo;
    lvl_tables(lvl, L, M, qo, kvo);
    const f16* qb = qBase + qo;
    const f16* kT = kBase + kvo;
    const f16* vb = vBase + kvo;
    f16* attT = attBase + qo;

    const int h = blockIdx.y, b = blockIdx.z;
    const int t = threadIdx.x, w = t >> 6, lane = t & 63;
    const int quad = lane >> 4, n16 = lane & 15;
    const size_t qbase = ((size_t)b * CCH + h * 4) * (size_t)L;
    const int mperm = ((n16 & 12) << 1) + (n16 & 3);  // (n16>>2)*8 + (n16&3)

    f16x8 qf[8];
    f32x4 acc[8];
    int tl0[8];
    bool valid[8];
    #pragma unroll
    for (int i = 0; i < 8; i++) {
        int tile = xl * 32 + i * 4 + w;
        tl0[i] = tile * 16;
        valid[i] = (tl0[i] < L);
        #pragma unroll
        for (int e = 0; e < 8; e++) qf[i][e] = (f16)0.f;
        acc[i][0] = 0.f; acc[i][1] = 0.f; acc[i][2] = 0.f; acc[i][3] = 0.f;
        if (valid[i] && quad == 0) {
            int l = tl0[i] + n16;
            #pragma unroll
            for (int d = 0; d < 4; d++) qf[i][d] = qb[qbase + (size_t)d * L + l];
        }
    }

    const f16* kp = kT + ((size_t)b * M) * CCH + h * 4;
    const f16* vp = vb + ((size_t)b * CCH + h * 4 + (n16 & 3)) * (size_t)M;

    f32x4 magic; magic[0] = SCH_MAGIC; magic[1] = SCH_MAGIC; magic[2] = SCH_MAGIC; magic[3] = SCH_MAGIC;

    for (int m0 = 0; m0 < M; m0 += 32) {
        f16x8 kf0, kf1;
        #pragma unroll
        for (int e = 0; e < 8; e++) { kf0[e] = (f16)0.f; kf1[e] = (f16)0.f; }
        if (quad == 0) {
            f16x4 ka = *(const f16x4*)(kp + (size_t)(m0 + mperm) * CCH);
            f16x4 kb4 = *(const f16x4*)(kp + (size_t)(m0 + mperm + 4) * CCH);
            #pragma unroll
            for (int d = 0; d < 4; d++) { kf0[d] = ka[d]; kf1[d] = kb4[d]; }
        }
        f16x8 vf;
        if (n16 < 4) {
            vf = *(const f16x8*)(vp + m0 + quad * 8);
        } else {
            f16 c = (f16)((n16 == 4) ? 1.f : ((n16 == 5 && m0 >= L) ? 1.f : 0.f));
            #pragma unroll
            for (int e = 0; e < 8; e++) vf[e] = c;
        }

        #pragma unroll
        for (int i = 0; i < 8; i++) {
            if (!valid[i]) continue;
            f32x4 s0 = __builtin_amdgcn_mfma_f32_16x16x32_f16(kf0, qf[i], magic, 0, 0, 0);
            f32x4 s1 = __builtin_amdgcn_mfma_f32_16x16x32_f16(kf1, qf[i], magic, 0, 0, 0);
            union { unsigned u[4]; f16x8 h; } W;
            W.u[0] = (unsigned)(int)s0[0] | ((unsigned)(int)s0[1] << 16);
            W.u[1] = (unsigned)(int)s0[2] | ((unsigned)(int)s0[3] << 16);
            W.u[2] = (unsigned)(int)s1[0] | ((unsigned)(int)s1[1] << 16);
            W.u[3] = (unsigned)(int)s1[2] | ((unsigned)(int)s1[3] << 16);
            acc[i] = __builtin_amdgcn_mfma_f32_16x16x32_f16(W.h, vf, acc[i], 0, 0, 0);
        }
    }

    float dsr = 0.f;
    #pragma unroll
    for (int i = 0; i < 8; i++) {
        if (!valid[i]) continue;
        #pragma unroll
        for (int r = 0; r < 4; r++) {
            float den = __shfl(acc[i][r], (lane & 48) | 4, 64);
            float rcp = 1.f / den;
            int l = tl0[i] + quad * 4 + r;
            if (n16 < 4)
                attT[((size_t)b * L + l) * CCH + h * 4 + n16] = (f16)(acc[i][r] * rcp);
            if (n16 == 5) dsr += acc[i][r] * rcp;
        }
    }
    dsr += __shfl_xor(dsr, 16, 64);
    dsr += __shfl_xor(dsr, 32, 64);
    if (n16 == 5 && quad == 0) atomicAdd(dsacc + (size_t)lvl * 128 + (size_t)b * 64 + h, dsr);
}

// ---------------- finalize ds ratios ----------------
__global__ void finalize_kernel(const float* __restrict__ dsacc, float* __restrict__ out) {
    int i = blockIdx.x;   // 0..7 = lvl*2+b
    int t = threadIdx.x;
    float v = dsacc[i * 64 + t];
    #pragma unroll
    for (int off = 32; off > 0; off >>= 1) v += __shfl_down(v, off);
    if (t == 0) {
        int lvl = i >> 1;
        int L = 4096 >> (2 * lvl);
        out[i] = v / (float)(HEADS * L);
    }
}

extern "C" void kernel_launch(void* const* d_in, const int* in_sizes, int n_in,
                              void* d_out, int out_size, void* d_ws, size_t ws_size,
                              hipStream_t stream) {
    const float* sp[4] = {(const float*)d_in[0], (const float*)d_in[1], (const float*)d_in[2], (const float*)d_in[3]};
    const float* iv[4] = {(const float*)d_in[4], (const float*)d_in[5], (const float*)d_in[6], (const float*)d_in[7]};
    const float* dd[4] = {(const float*)d_in[8], (const float*)d_in[9], (const float*)d_in[10], (const float*)d_in[11]};
    const float* Wq = (const float*)d_in[12];
    const float* bq = (const float*)d_in[13];
    const float* Wk = (const float*)d_in[14];
    const float* bk = (const float*)d_in[15];
    const float* Wv = (const float*)d_in[16];
    const float* bv = (const float*)d_in[17];
    const float* Wo = (const float*)d_in[18];
    const float* bo = (const float*)d_in[19];
    const float* Wdsk = (const float*)d_in[20];
    const float* bdsk = (const float*)d_in[21];
    const float* Wdsv = (const float*)d_in[22];
    const float* bdsv = (const float*)d_in[23];
    const float* gate = (const float*)d_in[24];

    float* ws = (float*)d_ws;
    float* pooled = ws + OFF_POOLED;
    float* dsacc = ws + OFF_DSACC;
    f16* hb = (f16*)((char*)d_ws + 10240);
    f16* qF   = hb + H_Q;
    f16* kF   = hb + H_K;
    f16* vF   = hb + H_V;
    f16* attF = hb + H_ATT;
    f16* spT  = hb + H_SPT;
    f16* ivT  = hb + H_IVT;
    f16* WF   = hb + H_W;
    float* out = (float*)d_out;

    hipMemsetAsync(dsacc, 0, 512 * sizeof(float), stream);

    pooled_kernel<<<dim3(256, 2, 4), 64, 0, stream>>>(dd[0], dd[1], dd[2], dd[3], pooled);
    wconv_kernel<<<dim3(256, 4), 256, 0, stream>>>(Wq, Wk, Wv, Wo, WF);

    P8 ptrs;
    for (int i = 0; i < 4; i++) { ptrs.a[i] = sp[i]; ptrs.a[4 + i] = iv[i]; }
    xpose_all_kernel<<<dim3(170, 8, 4), 256, 0, stream>>>(ptrs, spT, ivT);

    dstok_kernel<<<dim3(64, 4), 256, 0, stream>>>(Wdsk, bdsk, Wdsv, bdsv, gate, pooled, kF, vF);

    convqkv_kernel<<<dim3(43, 12, 2), 256, 0, stream>>>(spT, ivT, WF, bq, bk, bv, qF, kF, vF);

    attn_all_kernel<<<dim3(12, 64, 2), 256, 0, stream>>>(qF, kF, vF, attF, dsacc);

    convo_kernel<<<dim3(43, 4, 2), 256, 0, stream>>>(attF, WF, bo, sp[0], sp[1], sp[2], sp[3], out);

    finalize_kernel<<<dim3(8), 64, 0, stream>>>(dsacc, out + DS_OUT_OFF);
}